// Round 6
// baseline (132.226 us; speedup 1.0000x reference)
//
#include <hip/hip_runtime.h>
#include <hip/hip_bf16.h>

// Problem constants
#define IN_F   2048
#define N_CON  64
#define EMB    128
#define BATCH  8192

// Output layout (f32 elements): c_emb | c_pred | c_int | emb
#define CEMB_OFF  0
#define CPRED_OFF 67108864   // 8192*64*128
#define CINT_OFF  67633152   // + 8192*64
#define EMB_OFF   68157440   // + 8192*64

typedef __attribute__((ext_vector_type(4))) float f32x4;
typedef __attribute__((ext_vector_type(8))) short short8;
typedef __attribute__((ext_vector_type(4))) short short4v;

#define MFMA16(A,B,C) __builtin_amdgcn_mfma_f32_16x16x32_bf16((A),(B),(C),0,0,0)

__device__ __forceinline__ short f2bf(float f) {
  unsigned u = __float_as_uint(f);
  u += 0x7FFFu + ((u >> 16) & 1u);   // round-to-nearest-even
  return (short)(u >> 16);
}

__device__ __forceinline__ void gload_lds16(const void* g, void* l) {
  __builtin_amdgcn_global_load_lds(
      (const __attribute__((address_space(1))) unsigned*)g,
      (__attribute__((address_space(3))) unsigned*)l, 16, 0, 0);
}

// ---------------- kernel 0: f32 -> bf16 convert (We + Wc merged) ----------------
__global__ void conv2_kernel(const float* __restrict__ a, short* __restrict__ da, int n4a,
                             const float* __restrict__ b, short* __restrict__ db, int n4b) {
  int i = blockIdx.x * blockDim.x + threadIdx.x;
  const float* s; short* d; int j;
  if (i < n4a)            { s = a; d = da; j = i; }
  else if (i < n4a + n4b) { s = b; d = db; j = i - n4a; }
  else return;
  f32x4 v = *(const f32x4*)(s + (size_t)j * 4);
  short4v o;
  o.x = f2bf(v.x); o.y = f2bf(v.y); o.z = f2bf(v.z); o.w = f2bf(v.w);
  *(short4v*)(d + (size_t)j * 4) = o;
}

// ---------------- kernel 1: emb = leaky(x @ We^T + be) ----------------
// BM=16, grid 512, 256 threads (4 waves), LDS 36 KB -> 4 blocks/CU.
__global__ __launch_bounds__(256, 4)
void gemm1_kernel(const float* __restrict__ x,
                  const short* __restrict__ we_bf,   // [128][2048] bf16
                  const float* __restrict__ be,
                  float* __restrict__ out_emb,       // [8192][128] f32
                  short* __restrict__ emb_bf) {      // [8192][128] bf16
  __shared__ short As[16 * 128];    // 4 KB, XOR-swizzled
  __shared__ short Bs[128 * 128];   // 32 KB, XOR-swizzled

  const int t = threadIdx.x;
  const int w = t >> 6, l = t & 63;
  const int row0 = blockIdx.x * 16;

  f32x4 acc[2];
  acc[0] = (f32x4){0.f, 0.f, 0.f, 0.f};
  acc[1] = (f32x4){0.f, 0.f, 0.f, 0.f};

  const int ar = t >> 4;
  const int aseg = t & 15;
  const float* xrow = x + (size_t)(row0 + ar) * IN_F + aseg * 8;
  short* adst = &As[ar * 128 + ((aseg * 8) ^ ((ar & 7) << 3))];

  const int brl = t >> 4;
  const int bseg = l & 15;

  for (int kt = 0; kt < 16; ++kt) {
    const int k0 = kt * 128;
    {
      f32x4 v0 = *(const f32x4*)(xrow + k0);
      f32x4 v1 = *(const f32x4*)(xrow + k0 + 4);
      short8 o;
      o[0] = f2bf(v0.x); o[1] = f2bf(v0.y); o[2] = f2bf(v0.z); o[3] = f2bf(v0.w);
      o[4] = f2bf(v1.x); o[5] = f2bf(v1.y); o[6] = f2bf(v1.z); o[7] = f2bf(v1.w);
      *(short8*)adst = o;
    }
#pragma unroll
    for (int i = 0; i < 8; ++i) {
      int n = i * 16 + brl;
      gload_lds16(we_bf + (size_t)n * IN_F + k0 + ((bseg ^ (n & 7)) * 8),
                  &Bs[i * 2048 + w * 512]);
    }
    __syncthreads();
#pragma unroll
    for (int ks = 0; ks < 4; ++ks) {
      int kcol = ks * 32 + ((l >> 4) << 3);
      int r0 = l & 15;
      short8 a = *(const short8*)&As[r0 * 128 + (kcol ^ ((r0 & 7) << 3))];
      int n0 = w * 32 + (l & 15), n1 = n0 + 16;
      short8 b0 = *(const short8*)&Bs[n0 * 128 + (kcol ^ ((n0 & 7) << 3))];
      short8 b1 = *(const short8*)&Bs[n1 * 128 + (kcol ^ ((n1 & 7) << 3))];
      acc[0] = MFMA16(a, b0, acc[0]);
      acc[1] = MFMA16(a, b1, acc[1]);
    }
    __syncthreads();
  }

#pragma unroll
  for (int nf = 0; nf < 2; ++nf) {
    int e = w * 32 + nf * 16 + (l & 15);
    float bev = be[e];
#pragma unroll
    for (int r = 0; r < 4; ++r) {
      int b = row0 + ((l >> 4) << 2) + r;
      float v = acc[nf][r] + bev;
      v = v >= 0.f ? v : 0.01f * v;
      out_emb[(size_t)b * EMB + e] = v;
      emb_bf[(size_t)b * EMB + e] = f2bf(v);
    }
  }
}

// ---------------- kernel 2: fused context/gate/c_emb (v6) ----------------
// v5 structure (B in regs, per-wave A dbuf via global_load_lds, stores never
// drained, counted vmcnt) + LDS-bounced c_emb stores: gated values go through
// a per-pair LDS tile and are stored as dwordx4 with 64 contiguous lanes
// (4 rows x 256-B full-line segments) -- kills the 2x HBM write
// amplification measured in R4 (WRITE_SIZE 555 MB vs 270 logical).
// Two lgkm-only barriers per iter: (1) dot-partial exchange, (2) tile ready.
// Single-buffered pairbuf/tile are race-free under the 2-barrier scheme.
__global__ __launch_bounds__(512, 2)
void gemm2_kernel(const short* __restrict__ emb_bf,  // [8192][128] bf16
                  const short* __restrict__ wc_bf,   // [64][256][128] bf16
                  const float* __restrict__ bc,      // [64][256]
                  const float* __restrict__ wp,      // [256]
                  const float* __restrict__ bp,      // [1]
                  float* __restrict__ ws_pred,       // [64][8192]
                  float* __restrict__ out) {
  __shared__ short smem[32768];     // 64 KB: Bs (prologue) -> A buffers (loop)
  __shared__ float tile_s[4 * 16 * 132];  // 33 KB: per-pair gated-output tile
  __shared__ float pairbuf[128];    // dot-partial exchange

  const int t = threadIdx.x;
  const int w = t >> 6, l = t & 63;
  const int h = w & 1;              // half within pair
  const int p = w >> 1;             // pair 0..3
  const int q = l >> 4;             // lane quarter
  const int li = l & 15;
  const int lq = q << 3;
  const int kc = blockIdx.x & 63;
  const int mch = (blockIdx.x >> 6) * 512;

  // ---- prologue: stage B (64 KB) coalesced, then read into registers ----
  {
    const int rl = t >> 4;          // 0..31
#pragma unroll
    for (int i = 0; i < 8; ++i) {
      int rB = i * 32 + rl;
      gload_lds16(wc_bf + (size_t)kc * 32768 + (size_t)rB * 128 + ((li ^ (rB & 7)) * 8),
                  smem + i * 4096 + w * 512);
    }
  }
  float wph[8], bcv[8];
#pragma unroll
  for (int i = 0; i < 8; ++i) {
    int gg = (i & 3) + h * 4 + (i >> 2) * 8;
    wph[i] = wp[gg * 16 + li];
    bcv[i] = bc[kc * 256 + gg * 16 + li];
  }
  const float bp0 = bp[0];
  __syncthreads();                  // B in LDS

  short8 b[8][4];
#pragma unroll
  for (int i = 0; i < 8; ++i) {
    int gg = (i & 3) + h * 4 + (i >> 2) * 8;
    int n = gg * 16 + li;
#pragma unroll
    for (int ks = 0; ks < 4; ++ks)
      b[i][ks] = *(const short8*)&smem[n * 128 + ((ks * 32 + lq) ^ ((n & 7) << 3))];
  }
  __syncthreads();                  // all waves done reading B; recycle smem

  // per-wave A double-buffer: 4096 shorts (8 KB) at smem + w*4096
  short* bufA = smem + w * 4096;
  float* tp = tile_s + p * (16 * 132);
  const int R0 = mch + p * 16;

  // stage A(0) into buf half 0 (own wave only)
#pragma unroll
  for (int j = 0; j < 4; ++j) {
    int r = j * 4 + q;
    gload_lds16(emb_bf + (size_t)(R0 + r) * 128 + ((li ^ (r & 7)) * 8),
                bufA + j * 512);
  }
  asm volatile("s_waitcnt vmcnt(0)" ::: "memory");   // no stores yet: cheap

  int cur = 0;
  for (int it = 0; it < 8; ++it) {
    // A fragments from own buffer
    short8 a[4];
#pragma unroll
    for (int ks = 0; ks < 4; ++ks)
      a[ks] = *(const short8*)&bufA[cur * 2048 + li * 128 + ((ks * 32 + lq) ^ ((li & 7) << 3))];

    // prefetch A(it+1) into other half (4 vm loads, older than this iter's stores)
    if (it < 7) {
#pragma unroll
      for (int j = 0; j < 4; ++j) {
        int r = j * 4 + q;
        gload_lds16(emb_bf + (size_t)(R0 + (it + 1) * 64 + r) * 128 + ((li ^ (r & 7)) * 8),
                    bufA + (cur ^ 1) * 2048 + j * 512);
      }
    }

    // MFMA: 8 col-groups x 4 k-slices, C-init = bc
    f32x4 acc[8];
#pragma unroll
    for (int i = 0; i < 8; ++i)
      acc[i] = (f32x4){bcv[i], bcv[i], bcv[i], bcv[i]};
#pragma unroll
    for (int ks = 0; ks < 4; ++ks)
#pragma unroll
      for (int i = 0; i < 8; ++i)
        acc[i] = MFMA16(a[ks], b[i][ks], acc[i]);

    // leaky + own-half wp-dot
    f32x4 ps = (f32x4){0.f, 0.f, 0.f, 0.f};
#pragma unroll
    for (int i = 0; i < 8; ++i)
#pragma unroll
      for (int r = 0; r < 4; ++r) {
        float v = acc[i][r];
        v = fmaxf(v, 0.01f * v);
        acc[i][r] = v;
        ps[r] += v * wph[i];
      }
#pragma unroll
    for (int r = 0; r < 4; ++r) {
      float s = ps[r];
      s += __shfl_xor(s, 1);
      s += __shfl_xor(s, 2);
      s += __shfl_xor(s, 4);
      s += __shfl_xor(s, 8);
      ps[r] = s;                    // own-half dot for rows q*4+r (all lanes)
    }

    // ---- barrier 1: exchange dot halves ----
    if (li == 0) *(f32x4*)&pairbuf[(p * 2 + h) * 16 + q * 4] = ps;
    asm volatile("s_waitcnt lgkmcnt(0)\n\ts_barrier" ::: "memory");
    f32x4 po = *(const f32x4*)&pairbuf[(p * 2 + (h ^ 1)) * 16 + q * 4];

    float g[4];
#pragma unroll
    for (int r = 0; r < 4; ++r)
      g[r] = 1.f / (1.f + __expf(-(ps[r] + po[r] + bp0)));

    const int rowb = R0 + it * 64 + q * 4;
    // ws_pred store (x4, both halves store same value -> uniform vm count)
    {
      f32x4 gv; gv.x = g[0]; gv.y = g[1]; gv.z = g[2]; gv.w = g[3];
      if (li == 0) *(f32x4*)&ws_pred[(size_t)kc * 8192 + rowb] = gv;
    }

    // gated values -> per-pair tile (row q*4+r, col = own-half e)
#pragma unroll
    for (int i = 0; i < 4; ++i) {
      int e = (h * 4 + i) * 16 + li;
#pragma unroll
      for (int r = 0; r < 4; ++r) {
        float pos = acc[i][r], neg = acc[i + 4][r];
        tp[(q * 4 + r) * 132 + e] = neg + (pos - neg) * g[r];
      }
    }
    // ---- barrier 2: tile complete ----
    asm volatile("s_waitcnt lgkmcnt(0)\n\ts_barrier" ::: "memory");

    // coalesced c_emb stores: 4 x dwordx4, 64 lanes = 4 rows x 256 B each
    {
      const int prow0 = R0 + it * 64;
#pragma unroll
      for (int j = 0; j < 4; ++j) {
        int row_local = h * 8 + j * 2 + (l >> 5);
        int col4 = (l & 31) * 4;
        f32x4 v = *(const f32x4*)&tp[row_local * 132 + col4];
        *(f32x4*)&out[(size_t)(prow0 + row_local) * 8192 + kc * 128 + col4] = v;
      }
    }

    // retire own A-prefetch: 4 loads older than the 5 newest stores
    if (it < 7) asm volatile("s_waitcnt vmcnt(5)" ::: "memory");
    cur ^= 1;
  }
}

// ---------------- kernel 3: transpose ws_pred -> c_pred, c_int ----------------
__global__ __launch_bounds__(256)
void pred_tr_kernel(const float* __restrict__ ws_pred, float* __restrict__ out) {
  __shared__ float T[64][65];
  const int t = threadIdx.x;
  const int b0 = blockIdx.x * 64;

  {
    int kc = t >> 2;
    int j0 = (t & 3) * 16;
    const float* src = ws_pred + (size_t)kc * 8192 + b0 + j0;
#pragma unroll
    for (int i = 0; i < 4; ++i) {
      f32x4 v = *(const f32x4*)(src + i * 4);
      T[kc][j0 + i * 4 + 0] = v.x;
      T[kc][j0 + i * 4 + 1] = v.y;
      T[kc][j0 + i * 4 + 2] = v.z;
      T[kc][j0 + i * 4 + 3] = v.w;
    }
  }
  __syncthreads();
  {
    int bl = t & 63;
    int kq = (t >> 6) * 16;
#pragma unroll
    for (int i = 0; i < 4; ++i) {
      f32x4 v;
      v.x = T[kq + i * 4 + 0][bl];
      v.y = T[kq + i * 4 + 1][bl];
      v.z = T[kq + i * 4 + 2][bl];
      v.w = T[kq + i * 4 + 3][bl];
      *(f32x4*)&out[CPRED_OFF + (size_t)(b0 + bl) * 64 + kq + i * 4] = v;
      *(f32x4*)&out[CINT_OFF + (size_t)(b0 + bl) * 64 + kq + i * 4] = v;
    }
  }
}

extern "C" void kernel_launch(void* const* d_in, const int* in_sizes, int n_in,
                              void* d_out, int out_size, void* d_ws, size_t ws_size,
                              hipStream_t stream) {
  (void)in_sizes; (void)n_in; (void)out_size; (void)ws_size;
  const float* x  = (const float*)d_in[0];
  const float* We = (const float*)d_in[1];
  const float* be = (const float*)d_in[2];
  const float* Wc = (const float*)d_in[3];
  const float* bc = (const float*)d_in[4];
  const float* wp = (const float*)d_in[5];
  const float* bp = (const float*)d_in[6];
  float* out = (float*)d_out;

  // ws layout: We_bf16 (512KB) | Wc_bf16 (4MB) | emb_bf16 (2MB) | ws_pred (2MB f32)
  short* we_bf  = (short*)d_ws;
  short* wc_bf  = we_bf + 262144;
  short* emb_bf = wc_bf + 2097152;
  float* ws_pred = (float*)(emb_bf + 1048576);

  conv2_kernel<<<2304, 256, 0, stream>>>(We, we_bf, 65536, Wc, wc_bf, 524288);
  gemm1_kernel<<<512, 256, 0, stream>>>(x, we_bf, be, out + EMB_OFF, emb_bf);
  gemm2_kernel<<<1024, 512, 0, stream>>>(emb_bf, wc_bf, bc, wp, bp, ws_pred, out);
  pred_tr_kernel<<<128, 256, 0, stream>>>(ws_pred, out);
}